// Round 18
// baseline (457.622 us; speedup 1.0000x reference)
//
#include <hip/hip_runtime.h>
#include <math.h>

#define N_NODES 50000
#define N_EDGES 800000
#define R_REL 8
#define H_DIM 128
#define C_OUT 64

// k_xr geometry: block = (ro-chunk of 64) x (node-group of 4 tiles of 128)
#define XR_TILES 4
#define XR_NTILE ((N_NODES + 127) / 128)                    // 391
#define XR_NGRP ((XR_NTILE + XR_TILES - 1) / XR_TILES)      // 98
#define XR_XGRID (16 * XR_NGRP)                             // 1568
#define QK_BLOCKS ((N_NODES + 127) / 128)                   // 391 (512-thr, 128 nodes)

// CSR build: XCD-confined dst-range binning (verified round 11) + int4 edge reads
#define CSR_RANGES 8
#define CSR_RANGE_NODES (N_NODES / CSR_RANGES)   // 6250
#define CSR_BLOCKS 2048

typedef __attribute__((ext_vector_type(8))) __bf16 bf16x8;
typedef __attribute__((ext_vector_type(4))) __bf16 bf16x4;
typedef __attribute__((ext_vector_type(2))) __bf16 bf16x2;
typedef __attribute__((ext_vector_type(4))) float f32x4;

// async global->LDS, 16B per lane; dest must be wave-uniform base + lane*16
__device__ __forceinline__ void gload_lds16(const void* g, void* l) {
  __builtin_amdgcn_global_load_lds(
      (__attribute__((address_space(1))) void*)g,
      (__attribute__((address_space(3))) void*)l,
      16, 0, 0);
}

// ---------------- CSR build (dst-sorted edge list, packed (src<<3)|et) ----------------

__global__ void k_hist(const int* __restrict__ dst, int* __restrict__ hist) {
  const int rng = blockIdx.x & (CSR_RANGES - 1);
  const int rlo = rng * CSR_RANGE_NODES;
  const int rhi = rlo + CSR_RANGE_NODES;
  const int stride = (gridDim.x >> 3) * blockDim.x;
  const int4* dst4 = (const int4*)dst;
  for (int e = (blockIdx.x >> 3) * blockDim.x + threadIdx.x; e < N_EDGES / 4; e += stride) {
    int4 d = dst4[e];
    if (d.x >= rlo && d.x < rhi) atomicAdd(&hist[d.x], 1);
    if (d.y >= rlo && d.y < rhi) atomicAdd(&hist[d.y], 1);
    if (d.z >= rlo && d.z < rhi) atomicAdd(&hist[d.z], 1);
    if (d.w >= rlo && d.w < rhi) atomicAdd(&hist[d.w], 1);
  }
}

__global__ __launch_bounds__(1024) void k_scan1(const int* __restrict__ hist,
                                                int* __restrict__ excl, int* __restrict__ bsum) {
  __shared__ int tmp[1024];
  int b = blockIdx.x, tid = threadIdx.x;
  int idx = b * 1024 + tid;
  int v = (idx < N_NODES) ? hist[idx] : 0;
  tmp[tid] = v;
  __syncthreads();
  for (int off = 1; off < 1024; off <<= 1) {
    int t = (tid >= off) ? tmp[tid - off] : 0;
    __syncthreads();
    tmp[tid] += t;
    __syncthreads();
  }
  if (idx < N_NODES) excl[idx] = tmp[tid] - v;
  if (tid == 1023) bsum[b] = tmp[1023];
}

// 64-lane shfl prefix scan over the 49 block sums (was: 1-thread serial loop)
__global__ void k_scan2(const int* __restrict__ bsum, int* __restrict__ boff) {
  const int nb = (N_NODES + 1023) / 1024;   // 49
  int tid = threadIdx.x;
  int v = (tid < nb) ? bsum[tid] : 0;
  int s = v;
#pragma unroll
  for (int off = 1; off < 64; off <<= 1) {
    int t = __shfl_up(s, off);
    if (tid >= off) s += t;
  }
  if (tid < nb) boff[tid] = s - v;
}

__global__ void k_scan3(const int* __restrict__ excl, const int* __restrict__ boff,
                        int* __restrict__ rowptr, int* __restrict__ cursor) {
  int idx = blockIdx.x * blockDim.x + threadIdx.x;
  if (idx < N_NODES) {
    int v = excl[idx] + boff[idx >> 10];
    rowptr[idx] = v;
    cursor[idx] = v;
  }
  if (idx == 0) rowptr[N_NODES] = N_EDGES;
}

__global__ void k_scatter(const int* __restrict__ src, const int* __restrict__ dst,
                          const int* __restrict__ et, int* __restrict__ cursor,
                          int* __restrict__ spack) {
  const int rng = blockIdx.x & (CSR_RANGES - 1);
  const int rlo = rng * CSR_RANGE_NODES;
  const int rhi = rlo + CSR_RANGE_NODES;
  const int stride = (gridDim.x >> 3) * blockDim.x;
  const int4* dst4 = (const int4*)dst;
  const int4* src4 = (const int4*)src;
  const int4* et4  = (const int4*)et;
  for (int e = (blockIdx.x >> 3) * blockDim.x + threadIdx.x; e < N_EDGES / 4; e += stride) {
    int4 d = dst4[e];
    bool ax = d.x >= rlo && d.x < rhi;
    bool ay = d.y >= rlo && d.y < rhi;
    bool az = d.z >= rlo && d.z < rhi;
    bool aw = d.w >= rlo && d.w < rhi;
    if (ax | ay | az | aw) {
      int4 s4 = src4[e];
      int4 t4 = et4[e];
      if (ax) { int p = atomicAdd(&cursor[d.x], 1); spack[p] = (s4.x << 3) | t4.x; }
      if (ay) { int p = atomicAdd(&cursor[d.y], 1); spack[p] = (s4.y << 3) | t4.y; }
      if (az) { int p = atomicAdd(&cursor[d.z], 1); spack[p] = (s4.z << 3) | t4.z; }
      if (aw) { int p = atomicAdd(&cursor[d.w], 1); spack[p] = (s4.w << 3) | t4.w; }
    }
  }
}

// ---------------- x -> bf16 cast ----------------

__global__ void k_cast(const float* __restrict__ x, __bf16* __restrict__ xb) {
  int t = blockIdx.x * blockDim.x + threadIdx.x;
  if (t >= N_NODES * H_DIM / 8) return;
  const float4* xv = (const float4*)(x + (size_t)t * 8);
  float4 a = xv[0], b = xv[1];
  bf16x8 o;
  o[0] = (__bf16)a.x; o[1] = (__bf16)a.y; o[2] = (__bf16)a.z; o[3] = (__bf16)a.w;
  o[4] = (__bf16)b.x; o[5] = (__bf16)b.y; o[6] = (__bf16)b.z; o[7] = (__bf16)b.w;
  ((bf16x8*)xb)[t] = o;
}

// ---------------- merged weight prep: [0,192)=xrfrag, [192,204)=wq, [207,211)=lwfrag ----

__global__ void k_prep(const float* __restrict__ W1, const float* __restrict__ W2,
                       const float* __restrict__ W3,
                       const float* __restrict__ q1, const float* __restrict__ k1,
                       const float* __restrict__ q2, const float* __restrict__ k2,
                       const float* __restrict__ q3, const float* __restrict__ k3,
                       const float* __restrict__ lw,
                       __bf16* __restrict__ Ghi, __bf16* __restrict__ Glo,
                       float* __restrict__ wq, float* __restrict__ wk,
                       __bf16* __restrict__ Lhi, __bf16* __restrict__ Llo) {
  const int b = blockIdx.x;
  if (b < 192) {
    // xr fragments: 3*64*4*64 = 49152 items
    int t = b * 256 + threadIdx.x;
    int lane = t & 63;
    int kb = (t >> 6) & 3;
    int mt = (t >> 8) & 63;
    int l  = t >> 14;
    int c = lane & 15, quad = lane >> 4;
    const float* W = (l == 0) ? W1 : (l == 1) ? W2 : W3;
    int ro = mt * 16 + c;
    int r = ro >> 7;
    int o = ro & 127;
    int fb = kb * 32 + quad * 8;
    const float* wp = W + ((size_t)r << 14) + (size_t)fb * 128 + o;
    size_t ob = ((size_t)l * 131072) + (((size_t)mt * 4 + kb) * 64 + lane) * 8;
#pragma unroll
    for (int j = 0; j < 8; ++j) {
      float v = wp[j * 128];
      __bf16 h = (__bf16)v;
      Ghi[ob + j] = h;
      Glo[ob + j] = (__bf16)(v - (float)h);
    }
  } else if (b < 204) {
    // wq/wk: [l][r][f], 3*8*128 = 3072 items
    int idx = (b - 192) * 256 + threadIdx.x;
    if (idx >= 3 * R_REL * 128) return;
    int r = (idx >> 7) & 7;
    int f = idx & 127;
    int l = idx >> 10;
    const float* W  = (l == 0) ? W1 : (l == 1) ? W2 : W3;
    const float* qv = (l == 0) ? q1 : (l == 1) ? q2 : q3;
    const float* kv = (l == 0) ? k1 : (l == 1) ? k2 : k3;
    const float4* row = (const float4*)(W + ((size_t)r << 14) + ((size_t)f << 7));
    const float4* q4 = (const float4*)qv;
    const float4* k4 = (const float4*)kv;
    float sq = 0.f, sk = 0.f;
#pragma unroll 8
    for (int i = 0; i < 32; ++i) {
      float4 w = row[i], qq = q4[i], kk = k4[i];
      sq += w.x * qq.x + w.y * qq.y + w.z * qq.z + w.w * qq.w;
      sk += w.x * kk.x + w.y * kk.y + w.z * kk.z + w.w * kk.w;
    }
    wq[idx] = sq;
    wk[idx] = sk;
  } else if (b < 207) {
    return;   // (reserved; qkfrag depends on wq/wk -> separate kernel)
  } else {
    // lw fragments: [mt][kb][lane] = 4*4*64 = 1024 items
    int t = (b - 207) * 256 + threadIdx.x;
    if (t >= 1024) return;
    int lane = t & 63;
    int kb = (t >> 6) & 3;
    int mt = t >> 8;
    int c = lane & 15, quad = lane >> 4;
    int cout = mt * 16 + c;
    size_t ob = (size_t)t * 8;
#pragma unroll
    for (int j = 0; j < 8; ++j) {
      int k = kb * 32 + quad * 8 + j;
      float v = lw[(size_t)k * 64 + cout];
      __bf16 h = (__bf16)v;
      Lhi[ob + j] = h;
      Llo[ob + j] = (__bf16)(v - (float)h);
    }
  }
}

// ---------------- pack wq/wk into MFMA A-fragments (split-bf16) ----------------

__global__ void k_prepqkfrag(const float* __restrict__ wq, const float* __restrict__ wk,
                             __bf16* __restrict__ Qhi, __bf16* __restrict__ Qlo) {
  int t = blockIdx.x * 256 + threadIdx.x;   // 3*4*64 = 768
  if (t >= 768) return;
  int lane = t & 63;
  int kb = (t >> 6) & 3;
  int l  = t >> 8;
  int c = lane & 15, quad = lane >> 4;
  const float* Mrow = (c < 8) ? (wq + l * 1024 + c * 128) : (wk + l * 1024 + (c - 8) * 128);
  size_t ob = ((size_t)(l * 4 + kb) * 64 + lane) * 8;
#pragma unroll
  for (int j = 0; j < 8; ++j) {
    float v = Mrow[kb * 32 + quad * 8 + j];
    __bf16 h = (__bf16)v;
    Qhi[ob + j] = h;
    Qlo[ob + j] = (__bf16)(v - (float)h);
  }
}

// ---------------- XR GEMM + block-level fused qx/kx (verified round 17: -15 us) ---------

__global__ __launch_bounds__(512, 4) void k_xr(
    const __bf16* __restrict__ xin,
    const __bf16* __restrict__ Ghi, const __bf16* __restrict__ Glo,
    const __bf16* __restrict__ Qhi, const __bf16* __restrict__ Qlo,
    float* __restrict__ qx, float* __restrict__ kx,
    __bf16* __restrict__ XR)
{
  if (blockIdx.x >= XR_XGRID) {
    // ---- qkx path: 128 nodes per 512-thread block ----
    const int bq   = blockIdx.x - XR_XGRID;
    const int tid  = threadIdx.x;
    const int wave = tid >> 6;
    const int lane = tid & 63;
    const int quad = lane >> 4;
    const int c    = lane & 15;
    const int node = bq * 128 + wave * 16 + c;
    const int ncl  = (node < N_NODES) ? node : (N_NODES - 1);

    f32x4 acc = (f32x4){0.f, 0.f, 0.f, 0.f};
#pragma unroll
    for (int kb = 0; kb < 4; ++kb) {
      bf16x8 B = *(const bf16x8*)(xin + (size_t)ncl * 128 + kb * 32 + quad * 8);
      bf16x8 ah = ((const bf16x8*)Qhi)[kb * 64 + lane];
      bf16x8 al = ((const bf16x8*)Qlo)[kb * 64 + lane];
      acc = __builtin_amdgcn_mfma_f32_16x16x32_bf16(ah, B, acc, 0, 0, 0);
      acc = __builtin_amdgcn_mfma_f32_16x16x32_bf16(al, B, acc, 0, 0, 0);
    }
    if (node < N_NODES) {
      float* base = (quad & 2) ? kx : qx;
      int off = (quad & 1) * 4;
      *(float4*)(base + (size_t)node * 8 + off) = make_float4(acc[0], acc[1], acc[2], acc[3]);
    }
    return;
  }

  // ---- XR path ----
  __shared__ bf16x8 sW[2048];            // [0,1024) hi, [1024,2048) lo — 32 KB
  __shared__ __bf16 sT[8192];            // 8 waves x (16 nodes x 64 ro) — 16 KB
  const int tid  = threadIdx.x;
  const int wave = tid >> 6;
  const int lane = tid & 63;
  const int quad = lane >> 4;
  const int c    = lane & 15;
  const int ch   = blockIdx.x & 15;      // ro-chunk: 64 outputs
  const int grp  = blockIdx.x >> 4;      // node group of XR_TILES tiles

  char* sTw = (char*)(sT + wave * 1024); // this wave's 2 KB transpose buffer

  // stage this chunk's weights: 16 KB hi + 16 KB lo
  {
    const float4* gh = (const float4*)(Ghi + (size_t)ch * 8192);
    const float4* gl = (const float4*)(Glo + (size_t)ch * 8192);
    float4* s4 = (float4*)sW;
    gload_lds16(gh + tid, s4 + tid);
    gload_lds16(gh + tid + 512, s4 + tid + 512);
    gload_lds16(gl + tid, s4 + 1024 + tid);
    gload_lds16(gl + tid + 512, s4 + 1024 + tid + 512);
  }

  bool staged = false;
#pragma unroll 1
  for (int t = 0; t < XR_TILES; ++t) {
    const int nb = grp * XR_TILES + t;
    if (nb * 128 >= N_NODES) break;
    const int node = nb * 128 + wave * 16 + c;
    const int nclamp = (node < N_NODES) ? node : (N_NODES - 1);

    bf16x8 B[4];
#pragma unroll
    for (int kb = 0; kb < 4; ++kb)
      B[kb] = *(const bf16x8*)(xin + (size_t)nclamp * 128 + kb * 32 + quad * 8);

    if (!staged) {           // first tile: wait for weight stage (vmcnt drain + barrier)
      __syncthreads();
      staged = true;
    }

    f32x4 acc[4];
#pragma unroll
    for (int ot = 0; ot < 4; ++ot) acc[ot] = (f32x4){0.f, 0.f, 0.f, 0.f};
#pragma unroll
    for (int kb = 0; kb < 4; ++kb) {
#pragma unroll
      for (int ot = 0; ot < 4; ++ot) {
        bf16x8 whi = sW[(ot * 4 + kb) * 64 + lane];
        bf16x8 wlo = sW[1024 + (ot * 4 + kb) * 64 + lane];
        acc[ot] = __builtin_amdgcn_mfma_f32_16x16x32_bf16(whi, B[kb], acc[ot], 0, 0, 0);
        acc[ot] = __builtin_amdgcn_mfma_f32_16x16x32_bf16(wlo, B[kb], acc[ot], 0, 0, 0);
      }
    }

    // intra-wave transpose: acc (node c, ro = ot*16+quad*4+j) -> node-major rows.
#pragma unroll
    for (int ot = 0; ot < 4; ++ot) {
      bf16x4 o;
      o[0] = (__bf16)acc[ot][0];
      o[1] = (__bf16)acc[ot][1];
      o[2] = (__bf16)acc[ot][2];
      o[3] = (__bf16)acc[ot][3];
      int boff = (c << 7) + (((ot << 5) + (quad << 3)) ^ ((c & 7) << 4));
      *(bf16x4*)(sTw + boff) = o;
    }
    // same-wave DS ordering: compiler inserts lgkmcnt wait before dependent reads.
#pragma unroll
    for (int i = 0; i < 2; ++i) {
      int nl  = i * 8 + (lane >> 3);     // node_local 0..15
      int seg = lane & 7;                // 16B segment within the 128B row
      int boff = (nl << 7) + (((seg << 4)) ^ ((nl & 7) << 4));
      bf16x8 v = *(bf16x8*)(sTw + boff);
      int gn = nb * 128 + wave * 16 + nl;
      if (gn < N_NODES)
        *(bf16x8*)(XR + (size_t)gn * 1024 + ch * 64 + seg * 8) = v;
    }
  }
}

// ---------------- phase A: per-dst online-softmax over XR rows -> h (bias+relu fused) ----
// 16-lane groups, 4 nodes per wave (round 16: at gather-fetch floor ~120 MB).

__global__ __launch_bounds__(256) void k_agg_feat(
    const __bf16* __restrict__ XR, const float* __restrict__ qx, const float* __restrict__ kx,
    const int* __restrict__ rowptr, const int* __restrict__ spack,
    const float* __restrict__ bias, __bf16* __restrict__ hout)
{
  const int lane  = threadIdx.x & 63;
  const int g     = lane >> 4;         // group 0..3 within wave
  const int l16   = lane & 15;         // lane within group
  const int gbase = lane & 48;         // g*16
  const int nd = blockIdx.x * 16 + (threadIdx.x >> 6) * 4 + g;
  const bool alive = nd < N_NODES;

  const int s   = alive ? rowptr[nd] : 0;
  const int deg = alive ? rowptr[nd + 1] - s : 0;

  float m = -INFINITY, sum = 0.f;
  float acc[8];
#pragma unroll
  for (int d = 0; d < 8; ++d) acc[d] = 0.f;

  for (int c0 = 0; c0 < deg; c0 += 16) {
    int idx = c0 + l16;
    bool valid = idx < deg;
    int pk = valid ? spack[s + idx] : 0;
    float a = -INFINITY;
    if (valid) {
      float av = qx[(nd << 3) | (pk & 7)] + kx[pk];
      a = (av >= 0.f) ? av : 0.2f * av;   // leaky relu, slope 0.2
    }
    float cm = a;
#pragma unroll
    for (int off = 8; off > 0; off >>= 1) cm = fmaxf(cm, __shfl_xor(cm, off));
    if (c0 == 0) {
      m = cm;                 // first chunk: no rescale needed
    } else {
      float mnew = fmaxf(m, cm);
      float scale = __expf(m - mnew);
      sum *= scale;
#pragma unroll
      for (int d = 0; d < 8; ++d) acc[d] *= scale;
      m = mnew;
    }
    float ew = valid ? __expf(a - m) : 0.f;
    float cs = ew;
#pragma unroll
    for (int off = 8; off > 0; off >>= 1) cs += __shfl_xor(cs, off);
    sum += cs;

    int cnt = (deg - c0 < 16) ? (deg - c0) : 16;
#pragma unroll 1
    for (int j0 = 0; j0 < 16; j0 += 8) {
      if (j0 >= cnt) break;              // group-uniform
      int p[8];
      float w[8];
      bf16x8 v[8];
#pragma unroll
      for (int u = 0; u < 8; ++u) p[u] = __shfl(pk, gbase + j0 + u);
#pragma unroll
      for (int u = 0; u < 8; ++u) w[u] = __shfl(ew, gbase + j0 + u);
#pragma unroll
      for (int u = 0; u < 8; ++u)
        v[u] = ((const bf16x8*)(XR + ((size_t)p[u] << 7)))[l16];
#pragma unroll
      for (int u = 0; u < 8; ++u) {
#pragma unroll
        for (int d = 0; d < 8; ++d) acc[d] += w[u] * (float)v[u][d];
      }
    }
  }

  if (alive) {
    float inv = (deg > 0) ? 1.f / sum : 0.f;
    const float* bb = bias + l16 * 8;
    bf16x8 o;
#pragma unroll
    for (int d = 0; d < 8; ++d) o[d] = (__bf16)fmaxf(acc[d] * inv + bb[d], 0.f);
    ((bf16x8*)hout)[(size_t)nd * 16 + l16] = o;
  }
}

// ---------------- final linear + log_softmax via MFMA ----------------

__global__ __launch_bounds__(256) void k_final(
    const __bf16* __restrict__ h,
    const __bf16* __restrict__ Lhi, const __bf16* __restrict__ Llo,
    const float* __restrict__ lb, float* __restrict__ out)
{
  const int tid  = threadIdx.x;
  const int wave = tid >> 6;
  const int lane = tid & 63;
  const int quad = lane >> 4;
  const int c    = lane & 15;
  const int node = blockIdx.x * 64 + wave * 16 + c;
  const int ncl  = (node < N_NODES) ? node : (N_NODES - 1);

  bf16x8 B[4];
#pragma unroll
  for (int kb = 0; kb < 4; ++kb)
    B[kb] = *(const bf16x8*)(h + (size_t)ncl * 128 + kb * 32 + quad * 8);

  f32x4 acc[4];
#pragma unroll
  for (int mt = 0; mt < 4; ++mt) acc[mt] = (f32x4){0.f, 0.f, 0.f, 0.f};

#pragma unroll
  for (int mt = 0; mt < 4; ++mt) {
#pragma unroll
    for (int kb = 0; kb < 4; ++kb) {
      bf16x8 ah = ((const bf16x8*)Lhi)[(mt * 4 + kb) * 64 + lane];
      bf16x8 al = ((const bf16x8*)Llo)[(mt * 4 + kb) * 64 + lane];
      acc[mt] = __builtin_amdgcn_mfma_f32_16x16x32_bf16(ah, B[kb], acc[mt], 0, 0, 0);
      acc[mt] = __builtin_amdgcn_mfma_f32_16x16x32_bf16(al, B[kb], acc[mt], 0, 0, 0);
    }
  }

  float v[16];
#pragma unroll
  for (int mt = 0; mt < 4; ++mt) {
    float4 bb = *(const float4*)(lb + mt * 16 + quad * 4);
    v[mt * 4 + 0] = acc[mt][0] + bb.x;
    v[mt * 4 + 1] = acc[mt][1] + bb.y;
    v[mt * 4 + 2] = acc[mt][2] + bb.z;
    v[mt * 4 + 3] = acc[mt][3] + bb.w;
  }
  float mx = v[0];
#pragma unroll
  for (int i = 1; i < 16; ++i) mx = fmaxf(mx, v[i]);
  mx = fmaxf(mx, __shfl_xor(mx, 16));
  mx = fmaxf(mx, __shfl_xor(mx, 32));
  float ssum = 0.f;
#pragma unroll
  for (int i = 0; i < 16; ++i) ssum += __expf(v[i] - mx);
  ssum += __shfl_xor(ssum, 16);
  ssum += __shfl_xor(ssum, 32);
  float lse = mx + __logf(ssum);

  if (node < N_NODES) {
    float* op = out + (size_t)node * 64 + quad * 4;
#pragma unroll
    for (int mt = 0; mt < 4; ++mt) {
      *(float4*)(op + mt * 16) = make_float4(v[mt * 4 + 0] - lse, v[mt * 4 + 1] - lse,
                                             v[mt * 4 + 2] - lse, v[mt * 4 + 3] - lse);
    }
  }
}

// ---------------- launch ----------------

extern "C" void kernel_launch(void* const* d_in, const int* in_sizes, int n_in,
                              void* d_out, int out_size, void* d_ws, size_t ws_size,
                              hipStream_t stream) {
  const float* x   = (const float*)d_in[0];
  const int* ei    = (const int*)d_in[1];
  const int* etype = (const int*)d_in[2];
  const float* W1 = (const float*)d_in[3];
  const float* q1 = (const float*)d_in[4];
  const float* k1 = (const float*)d_in[5];
  const float* b1 = (const float*)d_in[6];
  const float* W2 = (const float*)d_in[7];
  const float* q2 = (const float*)d_in[8];
  const float* k2 = (const float*)d_in[9];
  const float* b2 = (const float*)d_in[10];
  const float* W3 = (const float*)d_in[11];
  const float* q3 = (const float*)d_in[12];
  const float* k3 = (const float*)d_in[13];
  const float* b3 = (const float*)d_in[14];
  const float* lw = (const float*)d_in[15];
  const float* lb = (const float*)d_in[16];
  float* outp = (float*)d_out;

  char* p = (char*)d_ws;
  auto alloc = [&](size_t bytes) {
    char* r = p;
    p += (bytes + 255) & ~(size_t)255;
    return r;
  };
  __bf16* XR  = (__bf16*)alloc((size_t)N_NODES * R_REL * H_DIM * 2);  // 102.4 MB
  __bf16* xb  = (__bf16*)alloc((size_t)N_NODES * H_DIM * 2);          // 12.8 MB
  __bf16* hA  = (__bf16*)alloc((size_t)N_NODES * H_DIM * 2);
  __bf16* hB  = (__bf16*)alloc((size_t)N_NODES * H_DIM * 2);
  float* qx   = (float*)alloc((size_t)N_NODES * R_REL * 4);
  float* kx   = (float*)alloc((size_t)N_NODES * R_REL * 4);
  int* rowptr = (int*)alloc((size_t)(N_NODES + 1) * 4);
  int* cursor = (int*)alloc((size_t)N_NODES * 4);
  int* hist   = (int*)alloc((size_t)N_NODES * 4);
  int* excl   = (int*)alloc((size_t)N_NODES * 4);
  int* bsum   = (int*)alloc((size_t)64 * 4);
  int* boff   = (int*)alloc((size_t)64 * 4);
  int* spack  = (int*)alloc((size_t)N_EDGES * 4);
  __bf16* Ghi = (__bf16*)alloc((size_t)3 * 131072 * 2);   // 786 KB
  __bf16* Glo = (__bf16*)alloc((size_t)3 * 131072 * 2);
  float* wq   = (float*)alloc((size_t)3 * R_REL * 128 * 4);
  float* wk   = (float*)alloc((size_t)3 * R_REL * 128 * 4);
  __bf16* Qhi = (__bf16*)alloc((size_t)3 * 2048 * 2);
  __bf16* Qlo = (__bf16*)alloc((size_t)3 * 2048 * 2);
  __bf16* Lhi = (__bf16*)alloc((size_t)1024 * 8 * 2);     // 16 KB
  __bf16* Llo = (__bf16*)alloc((size_t)1024 * 8 * 2);

  const int* src = ei;            // edge_index[0]
  const int* dst = ei + N_EDGES;  // edge_index[1]

  const int nscan = (N_NODES + 1023) / 1024;

  // CSR build + W prep + x cast
  hipMemsetAsync(hist, 0, (size_t)N_NODES * 4, stream);
  k_hist<<<CSR_BLOCKS, 256, 0, stream>>>(dst, hist);
  k_cast<<<(N_NODES * H_DIM / 8 + 255) / 256, 256, 0, stream>>>(x, xb);
  k_prep<<<211, 256, 0, stream>>>(W1, W2, W3, q1, k1, q2, k2, q3, k3, lw,
                                  Ghi, Glo, wq, wk, Lhi, Llo);
  k_prepqkfrag<<<3, 256, 0, stream>>>(wq, wk, Qhi, Qlo);
  k_scan1<<<nscan, 1024, 0, stream>>>(hist, excl, bsum);
  k_scan2<<<1, 64, 0, stream>>>(bsum, boff);
  k_scan3<<<(N_NODES + 255) / 256, 256, 0, stream>>>(excl, boff, rowptr, cursor);
  k_scatter<<<CSR_BLOCKS, 256, 0, stream>>>(src, dst, etype, cursor, spack);

  const int xgrid = XR_XGRID + QK_BLOCKS;   // xr blocks + fused qkx blocks
  const int agrid = (N_NODES + 15) / 16;
  const int fgrid = (N_NODES + 63) / 64;
  const size_t WFL = 131072;
  const size_t QFL = 2048;

  // layer 1
  k_xr<<<xgrid, 512, 0, stream>>>(xb, Ghi, Glo, Qhi, Qlo, qx, kx, XR);
  k_agg_feat<<<agrid, 256, 0, stream>>>(XR, qx, kx, rowptr, spack, b1, hA);
  // layer 2
  k_xr<<<xgrid, 512, 0, stream>>>(hA, Ghi + WFL, Glo + WFL, Qhi + QFL, Qlo + QFL, qx, kx, XR);
  k_agg_feat<<<agrid, 256, 0, stream>>>(XR, qx, kx, rowptr, spack, b2, hB);
  // layer 3
  k_xr<<<xgrid, 512, 0, stream>>>(hB, Ghi + 2 * WFL, Glo + 2 * WFL, Qhi + 2 * QFL, Qlo + 2 * QFL, qx, kx, XR);
  k_agg_feat<<<agrid, 256, 0, stream>>>(XR, qx, kx, rowptr, spack, b3, hA);
  // final linear + log_softmax (MFMA)
  k_final<<<fgrid, 256, 0, stream>>>(hA, Lhi, Llo, lb, outp);
}

// Round 19
// 444.620 us; speedup vs baseline: 1.0292x; 1.0292x over previous
//
#include <hip/hip_runtime.h>
#include <math.h>

#define N_NODES 50000
#define N_EDGES 800000
#define R_REL 8
#define H_DIM 128
#define C_OUT 64

// k_xr geometry: block = (ro-chunk of 64) x (node-group of 4 tiles of 128)
#define XR_TILES 4
#define XR_NTILE ((N_NODES + 127) / 128)                    // 391
#define XR_NGRP ((XR_NTILE + XR_TILES - 1) / XR_TILES)      // 98
#define XR_XGRID (16 * XR_NGRP)                             // 1568
#define QK_BLOCKS ((N_NODES + 127) / 128)                   // 391 (512-thr, 128 nodes)

// CSR build: XCD-confined dst-range binning (verified round 11); scalar loops
// (round 18: int4 variant null/noise-worse -> reverted)
#define CSR_RANGES 8
#define CSR_RANGE_NODES (N_NODES / CSR_RANGES)   // 6250
#define CSR_BLOCKS 2048

// k_prep block ranges
#define PREP_B_XR 192                     // xr fragments
#define PREP_B_WQ 204                     // + wq/wk
#define PREP_B_LW0 207
#define PREP_B_LW 211                     // + lw fragments
#define PREP_B_HZ (PREP_B_LW + 196)       // + zero hist (50000 ints)
#define PREP_B_CAST (PREP_B_HZ + 3125)    // + x->bf16 cast (800000 items)

typedef __attribute__((ext_vector_type(8))) __bf16 bf16x8;
typedef __attribute__((ext_vector_type(4))) __bf16 bf16x4;
typedef __attribute__((ext_vector_type(2))) __bf16 bf16x2;
typedef __attribute__((ext_vector_type(4))) float f32x4;

// async global->LDS, 16B per lane; dest must be wave-uniform base + lane*16
__device__ __forceinline__ void gload_lds16(const void* g, void* l) {
  __builtin_amdgcn_global_load_lds(
      (__attribute__((address_space(1))) void*)g,
      (__attribute__((address_space(3))) void*)l,
      16, 0, 0);
}

// ---------------- CSR build (dst-sorted edge list, packed (src<<3)|et) ----------------

__global__ void k_hist(const int* __restrict__ dst, int* __restrict__ hist) {
  const int rng = blockIdx.x & (CSR_RANGES - 1);
  const int rlo = rng * CSR_RANGE_NODES;
  const int rhi = rlo + CSR_RANGE_NODES;
  const int stride = (gridDim.x >> 3) * blockDim.x;
  for (int e = (blockIdx.x >> 3) * blockDim.x + threadIdx.x; e < N_EDGES; e += stride) {
    int d = dst[e];
    if (d >= rlo && d < rhi) atomicAdd(&hist[d], 1);
  }
}

// scan1 blocks [0,49): block-level prefix over hist.  block 49: qkfrag packing
// (dep: k_prep's wq/wk — upstream dispatch).  Early return is block-uniform.
__global__ __launch_bounds__(1024) void k_scan1(const int* __restrict__ hist,
                                                int* __restrict__ excl, int* __restrict__ bsum,
                                                const float* __restrict__ wq,
                                                const float* __restrict__ wk,
                                                __bf16* __restrict__ Qhi,
                                                __bf16* __restrict__ Qlo) {
  int b = blockIdx.x, tid = threadIdx.x;
  if (b >= 49) {
    // qkfrag: 3*4*64 = 768 items
    int t = tid;
    if (t >= 768) return;
    int lane = t & 63;
    int kb = (t >> 6) & 3;
    int l  = t >> 8;
    int c = lane & 15, quad = lane >> 4;
    const float* Mrow = (c < 8) ? (wq + l * 1024 + c * 128) : (wk + l * 1024 + (c - 8) * 128);
    size_t ob = ((size_t)(l * 4 + kb) * 64 + lane) * 8;
#pragma unroll
    for (int j = 0; j < 8; ++j) {
      float v = Mrow[kb * 32 + quad * 8 + j];
      __bf16 h = (__bf16)v;
      Qhi[ob + j] = h;
      Qlo[ob + j] = (__bf16)(v - (float)h);
    }
    return;
  }
  __shared__ int tmp[1024];
  int idx = b * 1024 + tid;
  int v = (idx < N_NODES) ? hist[idx] : 0;
  tmp[tid] = v;
  __syncthreads();
  for (int off = 1; off < 1024; off <<= 1) {
    int t = (tid >= off) ? tmp[tid - off] : 0;
    __syncthreads();
    tmp[tid] += t;
    __syncthreads();
  }
  if (idx < N_NODES) excl[idx] = tmp[tid] - v;
  if (tid == 1023) bsum[b] = tmp[1023];
}

// 64-lane shfl prefix scan over the 49 block sums
__global__ void k_scan2(const int* __restrict__ bsum, int* __restrict__ boff) {
  const int nb = (N_NODES + 1023) / 1024;   // 49
  int tid = threadIdx.x;
  int v = (tid < nb) ? bsum[tid] : 0;
  int s = v;
#pragma unroll
  for (int off = 1; off < 64; off <<= 1) {
    int t = __shfl_up(s, off);
    if (tid >= off) s += t;
  }
  if (tid < nb) boff[tid] = s - v;
}

__global__ void k_scan3(const int* __restrict__ excl, const int* __restrict__ boff,
                        int* __restrict__ rowptr, int* __restrict__ cursor) {
  int idx = blockIdx.x * blockDim.x + threadIdx.x;
  if (idx < N_NODES) {
    int v = excl[idx] + boff[idx >> 10];
    rowptr[idx] = v;
    cursor[idx] = v;
  }
  if (idx == 0) rowptr[N_NODES] = N_EDGES;
}

__global__ void k_scatter(const int* __restrict__ src, const int* __restrict__ dst,
                          const int* __restrict__ et, int* __restrict__ cursor,
                          int* __restrict__ spack) {
  const int rng = blockIdx.x & (CSR_RANGES - 1);
  const int rlo = rng * CSR_RANGE_NODES;
  const int rhi = rlo + CSR_RANGE_NODES;
  const int stride = (gridDim.x >> 3) * blockDim.x;
  for (int e = (blockIdx.x >> 3) * blockDim.x + threadIdx.x; e < N_EDGES; e += stride) {
    int d = dst[e];
    if (d >= rlo && d < rhi) {
      int p = atomicAdd(&cursor[d], 1);
      spack[p] = (src[e] << 3) | et[e];
    }
  }
}

// ---------------- merged prep: xrfrag + wq + lwfrag + zero-hist + x->bf16 cast ----------

__global__ void k_prep(const float* __restrict__ W1, const float* __restrict__ W2,
                       const float* __restrict__ W3,
                       const float* __restrict__ q1, const float* __restrict__ k1,
                       const float* __restrict__ q2, const float* __restrict__ k2,
                       const float* __restrict__ q3, const float* __restrict__ k3,
                       const float* __restrict__ lw, const float* __restrict__ x,
                       __bf16* __restrict__ Ghi, __bf16* __restrict__ Glo,
                       float* __restrict__ wq, float* __restrict__ wk,
                       __bf16* __restrict__ Lhi, __bf16* __restrict__ Llo,
                       int* __restrict__ hist, __bf16* __restrict__ xb) {
  const int b = blockIdx.x;
  if (b < PREP_B_XR) {
    // xr fragments: 3*64*4*64 = 49152 items
    int t = b * 256 + threadIdx.x;
    int lane = t & 63;
    int kb = (t >> 6) & 3;
    int mt = (t >> 8) & 63;
    int l  = t >> 14;
    int c = lane & 15, quad = lane >> 4;
    const float* W = (l == 0) ? W1 : (l == 1) ? W2 : W3;
    int ro = mt * 16 + c;
    int r = ro >> 7;
    int o = ro & 127;
    int fb = kb * 32 + quad * 8;
    const float* wp = W + ((size_t)r << 14) + (size_t)fb * 128 + o;
    size_t ob = ((size_t)l * 131072) + (((size_t)mt * 4 + kb) * 64 + lane) * 8;
#pragma unroll
    for (int j = 0; j < 8; ++j) {
      float v = wp[j * 128];
      __bf16 h = (__bf16)v;
      Ghi[ob + j] = h;
      Glo[ob + j] = (__bf16)(v - (float)h);
    }
  } else if (b < PREP_B_WQ) {
    // wq/wk: [l][r][f], 3*8*128 = 3072 items
    int idx = (b - PREP_B_XR) * 256 + threadIdx.x;
    if (idx >= 3 * R_REL * 128) return;
    int r = (idx >> 7) & 7;
    int f = idx & 127;
    int l = idx >> 10;
    const float* W  = (l == 0) ? W1 : (l == 1) ? W2 : W3;
    const float* qv = (l == 0) ? q1 : (l == 1) ? q2 : q3;
    const float* kv = (l == 0) ? k1 : (l == 1) ? k2 : k3;
    const float4* row = (const float4*)(W + ((size_t)r << 14) + ((size_t)f << 7));
    const float4* q4 = (const float4*)qv;
    const float4* k4 = (const float4*)kv;
    float sq = 0.f, sk = 0.f;
#pragma unroll 8
    for (int i = 0; i < 32; ++i) {
      float4 w = row[i], qq = q4[i], kk = k4[i];
      sq += w.x * qq.x + w.y * qq.y + w.z * qq.z + w.w * qq.w;
      sk += w.x * kk.x + w.y * kk.y + w.z * kk.z + w.w * kk.w;
    }
    wq[idx] = sq;
    wk[idx] = sk;
  } else if (b < PREP_B_LW0) {
    return;   // reserved
  } else if (b < PREP_B_LW) {
    // lw fragments: [mt][kb][lane] = 4*4*64 = 1024 items
    int t = (b - PREP_B_LW0) * 256 + threadIdx.x;
    if (t >= 1024) return;
    int lane = t & 63;
    int kb = (t >> 6) & 3;
    int mt = t >> 8;
    int c = lane & 15, quad = lane >> 4;
    int cout = mt * 16 + c;
    size_t ob = (size_t)t * 8;
#pragma unroll
    for (int j = 0; j < 8; ++j) {
      int k = kb * 32 + quad * 8 + j;
      float v = lw[(size_t)k * 64 + cout];
      __bf16 h = (__bf16)v;
      Lhi[ob + j] = h;
      Llo[ob + j] = (__bf16)(v - (float)h);
    }
  } else if (b < PREP_B_HZ) {
    // zero hist (replaces hipMemsetAsync dispatch)
    int idx = (b - PREP_B_LW) * 256 + threadIdx.x;
    if (idx < N_NODES) hist[idx] = 0;
  } else {
    // x -> bf16 cast: 800000 bf16x8 items
    int t = (b - PREP_B_HZ) * 256 + threadIdx.x;
    if (t >= N_NODES * H_DIM / 8) return;
    const float4* xv = (const float4*)(x + (size_t)t * 8);
    float4 a = xv[0], bb = xv[1];
    bf16x8 o;
    o[0] = (__bf16)a.x;  o[1] = (__bf16)a.y;  o[2] = (__bf16)a.z;  o[3] = (__bf16)a.w;
    o[4] = (__bf16)bb.x; o[5] = (__bf16)bb.y; o[6] = (__bf16)bb.z; o[7] = (__bf16)bb.w;
    ((bf16x8*)xb)[t] = o;
  }
}

// ---------------- XR GEMM + block-level fused qx/kx (verified round 17: -15 us) ---------

__global__ __launch_bounds__(512, 4) void k_xr(
    const __bf16* __restrict__ xin,
    const __bf16* __restrict__ Ghi, const __bf16* __restrict__ Glo,
    const __bf16* __restrict__ Qhi, const __bf16* __restrict__ Qlo,
    float* __restrict__ qx, float* __restrict__ kx,
    __bf16* __restrict__ XR)
{
  if (blockIdx.x >= XR_XGRID) {
    // ---- qkx path: 128 nodes per 512-thread block ----
    const int bq   = blockIdx.x - XR_XGRID;
    const int tid  = threadIdx.x;
    const int wave = tid >> 6;
    const int lane = tid & 63;
    const int quad = lane >> 4;
    const int c    = lane & 15;
    const int node = bq * 128 + wave * 16 + c;
    const int ncl  = (node < N_NODES) ? node : (N_NODES - 1);

    f32x4 acc = (f32x4){0.f, 0.f, 0.f, 0.f};
#pragma unroll
    for (int kb = 0; kb < 4; ++kb) {
      bf16x8 B = *(const bf16x8*)(xin + (size_t)ncl * 128 + kb * 32 + quad * 8);
      bf16x8 ah = ((const bf16x8*)Qhi)[kb * 64 + lane];
      bf16x8 al = ((const bf16x8*)Qlo)[kb * 64 + lane];
      acc = __builtin_amdgcn_mfma_f32_16x16x32_bf16(ah, B, acc, 0, 0, 0);
      acc = __builtin_amdgcn_mfma_f32_16x16x32_bf16(al, B, acc, 0, 0, 0);
    }
    if (node < N_NODES) {
      float* base = (quad & 2) ? kx : qx;
      int off = (quad & 1) * 4;
      *(float4*)(base + (size_t)node * 8 + off) = make_float4(acc[0], acc[1], acc[2], acc[3]);
    }
    return;
  }

  // ---- XR path ----
  __shared__ bf16x8 sW[2048];            // [0,1024) hi, [1024,2048) lo — 32 KB
  __shared__ __bf16 sT[8192];            // 8 waves x (16 nodes x 64 ro) — 16 KB
  const int tid  = threadIdx.x;
  const int wave = tid >> 6;
  const int lane = tid & 63;
  const int quad = lane >> 4;
  const int c    = lane & 15;
  const int ch   = blockIdx.x & 15;      // ro-chunk: 64 outputs
  const int grp  = blockIdx.x >> 4;      // node group of XR_TILES tiles

  char* sTw = (char*)(sT + wave * 1024); // this wave's 2 KB transpose buffer

  // stage this chunk's weights: 16 KB hi + 16 KB lo
  {
    const float4* gh = (const float4*)(Ghi + (size_t)ch * 8192);
    const float4* gl = (const float4*)(Glo + (size_t)ch * 8192);
    float4* s4 = (float4*)sW;
    gload_lds16(gh + tid, s4 + tid);
    gload_lds16(gh + tid + 512, s4 + tid + 512);
    gload_lds16(gl + tid, s4 + 1024 + tid);
    gload_lds16(gl + tid + 512, s4 + 1024 + tid + 512);
  }

  bool staged = false;
#pragma unroll 1
  for (int t = 0; t < XR_TILES; ++t) {
    const int nb = grp * XR_TILES + t;
    if (nb * 128 >= N_NODES) break;
    const int node = nb * 128 + wave * 16 + c;
    const int nclamp = (node < N_NODES) ? node : (N_NODES - 1);

    bf16x8 B[4];
#pragma unroll
    for (int kb = 0; kb < 4; ++kb)
      B[kb] = *(const bf16x8*)(xin + (size_t)nclamp * 128 + kb * 32 + quad * 8);

    if (!staged) {           // first tile: wait for weight stage (vmcnt drain + barrier)
      __syncthreads();
      staged = true;
    }

    f32x4 acc[4];
#pragma unroll
    for (int ot = 0; ot < 4; ++ot) acc[ot] = (f32x4){0.f, 0.f, 0.f, 0.f};
#pragma unroll
    for (int kb = 0; kb < 4; ++kb) {
#pragma unroll
      for (int ot = 0; ot < 4; ++ot) {
        bf16x8 whi = sW[(ot * 4 + kb) * 64 + lane];
        bf16x8 wlo = sW[1024 + (ot * 4 + kb) * 64 + lane];
        acc[ot] = __builtin_amdgcn_mfma_f32_16x16x32_bf16(whi, B[kb], acc[ot], 0, 0, 0);
        acc[ot] = __builtin_amdgcn_mfma_f32_16x16x32_bf16(wlo, B[kb], acc[ot], 0, 0, 0);
      }
    }

    // intra-wave transpose: acc (node c, ro = ot*16+quad*4+j) -> node-major rows.
#pragma unroll
    for (int ot = 0; ot < 4; ++ot) {
      bf16x4 o;
      o[0] = (__bf16)acc[ot][0];
      o[1] = (__bf16)acc[ot][1];
      o[2] = (__bf16)acc[ot][2];
      o[3] = (__bf16)acc[ot][3];
      int boff = (c << 7) + (((ot << 5) + (quad << 3)) ^ ((c & 7) << 4));
      *(bf16x4*)(sTw + boff) = o;
    }
    // same-wave DS ordering: compiler inserts lgkmcnt wait before dependent reads.
#pragma unroll
    for (int i = 0; i < 2; ++i) {
      int nl  = i * 8 + (lane >> 3);     // node_local 0..15
      int seg = lane & 7;                // 16B segment within the 128B row
      int boff = (nl << 7) + (((seg << 4)) ^ ((nl & 7) << 4));
      bf16x8 v = *(bf16x8*)(sTw + boff);
      int gn = nb * 128 + wave * 16 + nl;
      if (gn < N_NODES)
        *(bf16x8*)(XR + (size_t)gn * 1024 + ch * 64 + seg * 8) = v;
    }
  }
}

// ---------------- phase A: per-dst online-softmax over XR rows -> h (bias+relu fused) ----
// 16-lane groups, 4 nodes per wave (round 16: at gather-fetch floor ~120 MB).

__global__ __launch_bounds__(256) void k_agg_feat(
    const __bf16* __restrict__ XR, const float* __restrict__ qx, const float* __restrict__ kx,
    const int* __restrict__ rowptr, const int* __restrict__ spack,
    const float* __restrict__ bias, __bf16* __restrict__ hout)
{
  const int lane  = threadIdx.x & 63;
  const int g     = lane >> 4;         // group 0..3 within wave
  const int l16   = lane & 15;         // lane within group
  const int gbase = lane & 48;         // g*16
  const int nd = blockIdx.x * 16 + (threadIdx.x >> 6) * 4 + g;
  const bool alive = nd < N_NODES;

  const int s   = alive ? rowptr[nd] : 0;
  const int deg = alive ? rowptr[nd + 1] - s : 0;

  float m = -INFINITY, sum = 0.f;
  float acc[8];
#pragma unroll
  for (int d = 0; d < 8; ++d) acc[d] = 0.f;

  for (int c0 = 0; c0 < deg; c0 += 16) {
    int idx = c0 + l16;
    bool valid = idx < deg;
    int pk = valid ? spack[s + idx] : 0;
    float a = -INFINITY;
    if (valid) {
      float av = qx[(nd << 3) | (pk & 7)] + kx[pk];
      a = (av >= 0.f) ? av : 0.2f * av;   // leaky relu, slope 0.2
    }
    float cm = a;
#pragma unroll
    for (int off = 8; off > 0; off >>= 1) cm = fmaxf(cm, __shfl_xor(cm, off));
    if (c0 == 0) {
      m = cm;                 // first chunk: no rescale needed
    } else {
      float mnew = fmaxf(m, cm);
      float scale = __expf(m - mnew);
      sum *= scale;
#pragma unroll
      for (int d = 0; d < 8; ++d) acc[d] *= scale;
      m = mnew;
    }
    float ew = valid ? __expf(a - m) : 0.f;
    float cs = ew;
#pragma unroll
    for (int off = 8; off > 0; off >>= 1) cs += __shfl_xor(cs, off);
    sum += cs;

    int cnt = (deg - c0 < 16) ? (deg - c0) : 16;
#pragma unroll 1
    for (int j0 = 0; j0 < 16; j0 += 8) {
      if (j0 >= cnt) break;              // group-uniform
      int p[8];
      float w[8];
      bf16x8 v[8];
#pragma unroll
      for (int u = 0; u < 8; ++u) p[u] = __shfl(pk, gbase + j0 + u);
#pragma unroll
      for (int u = 0; u < 8; ++u) w[u] = __shfl(ew, gbase + j0 + u);
#pragma unroll
      for (int u = 0; u < 8; ++u)
        v[u] = ((const bf16x8*)(XR + ((size_t)p[u] << 7)))[l16];
#pragma unroll
      for (int u = 0; u < 8; ++u) {
#pragma unroll
        for (int d = 0; d < 8; ++d) acc[d] += w[u] * (float)v[u][d];
      }
    }
  }

  if (alive) {
    float inv = (deg > 0) ? 1.f / sum : 0.f;
    const float* bb = bias + l16 * 8;
    bf16x8 o;
#pragma unroll
    for (int d = 0; d < 8; ++d) o[d] = (__bf16)fmaxf(acc[d] * inv + bb[d], 0.f);
    ((bf16x8*)hout)[(size_t)nd * 16 + l16] = o;
  }
}

// ---------------- final linear + log_softmax via MFMA ----------------

__global__ __launch_bounds__(256) void k_final(
    const __bf16* __restrict__ h,
    const __bf16* __restrict__ Lhi, const __bf16* __restrict__ Llo,
    const float* __restrict__ lb, float* __restrict__ out)
{
  const int tid  = threadIdx.x;
  const int wave = tid >> 6;
  const int lane = tid & 63;
  const int quad = lane >> 4;
  const int c    = lane & 15;
  const int node = blockIdx.x * 64 + wave * 16 + c;
  const int ncl  = (node < N_NODES) ? node : (N_NODES - 1);

  bf16x8 B[4];
#pragma unroll
  for (int kb = 0; kb < 4; ++kb)
    B[kb] = *(const bf16x8*)(h + (size_t)ncl * 128 + kb * 32 + quad * 8);

  f32x4 acc[4];
#pragma unroll
  for (int mt = 0; mt < 4; ++mt) acc[mt] = (f32x4){0.f, 0.f, 0.f, 0.f};

#pragma unroll
  for (int mt = 0; mt < 4; ++mt) {
#pragma unroll
    for (int kb = 0; kb < 4; ++kb) {
      bf16x8 ah = ((const bf16x8*)Lhi)[(mt * 4 + kb) * 64 + lane];
      bf16x8 al = ((const bf16x8*)Llo)[(mt * 4 + kb) * 64 + lane];
      acc[mt] = __builtin_amdgcn_mfma_f32_16x16x32_bf16(ah, B[kb], acc[mt], 0, 0, 0);
      acc[mt] = __builtin_amdgcn_mfma_f32_16x16x32_bf16(al, B[kb], acc[mt], 0, 0, 0);
    }
  }

  float v[16];
#pragma unroll
  for (int mt = 0; mt < 4; ++mt) {
    float4 bb = *(const float4*)(lb + mt * 16 + quad * 4);
    v[mt * 4 + 0] = acc[mt][0] + bb.x;
    v[mt * 4 + 1] = acc[mt][1] + bb.y;
    v[mt * 4 + 2] = acc[mt][2] + bb.z;
    v[mt * 4 + 3] = acc[mt][3] + bb.w;
  }
  float mx = v[0];
#pragma unroll
  for (int i = 1; i < 16; ++i) mx = fmaxf(mx, v[i]);
  mx = fmaxf(mx, __shfl_xor(mx, 16));
  mx = fmaxf(mx, __shfl_xor(mx, 32));
  float ssum = 0.f;
#pragma unroll
  for (int i = 0; i < 16; ++i) ssum += __expf(v[i] - mx);
  ssum += __shfl_xor(ssum, 16);
  ssum += __shfl_xor(ssum, 32);
  float lse = mx + __logf(ssum);

  if (node < N_NODES) {
    float* op = out + (size_t)node * 64 + quad * 4;
#pragma unroll
    for (int mt = 0; mt < 4; ++mt) {
      *(float4*)(op + mt * 16) = make_float4(v[mt * 4 + 0] - lse, v[mt * 4 + 1] - lse,
                                             v[mt * 4 + 2] - lse, v[mt * 4 + 3] - lse);
    }
  }
}

// ---------------- launch ----------------

extern "C" void kernel_launch(void* const* d_in, const int* in_sizes, int n_in,
                              void* d_out, int out_size, void* d_ws, size_t ws_size,
                              hipStream_t stream) {
  const float* x   = (const float*)d_in[0];
  const int* ei    = (const int*)d_in[1];
  const int* etype = (const int*)d_in[2];
  const float* W1 = (const float*)d_in[3];
  const float* q1 = (const float*)d_in[4];
  const float* k1 = (const float*)d_in[5];
  const float* b1 = (const float*)d_in[6];
  const float* W2 = (const float*)d_in[7];
  const float* q2 = (const float*)d_in[8];
  const float* k2 = (const float*)d_in[9];
  const float* b2 = (const float*)d_in[10];
  const float* W3 = (const float*)d_in[11];
  const float* q3 = (const float*)d_in[12];
  const float* k3 = (const float*)d_in[13];
  const float* b3 = (const float*)d_in[14];
  const float* lw = (const float*)d_in[15];
  const float* lb = (const float*)d_in[16];
  float* outp = (float*)d_out;

  char* p = (char*)d_ws;
  auto alloc = [&](size_t bytes) {
    char* r = p;
    p += (bytes + 255) & ~(size_t)255;
    return r;
  };
  __bf16* XR  = (__bf16*)alloc((size_t)N_NODES * R_REL * H_DIM * 2);  // 102.4 MB
  __bf16* xb  = (__bf16*)alloc((size_t)N_NODES * H_DIM * 2);          // 12.8 MB
  __bf16* hA  = (__bf16*)alloc((size_t)N_NODES * H_DIM * 2);
  __bf16* hB  = (__bf16*)alloc((size_t)N_NODES * H_DIM * 2);
  float* qx   = (float*)alloc((size_t)N_NODES * R_REL * 4);
  float* kx   = (float*)alloc((size_t)N_NODES * R_REL * 4);
  int* rowptr = (int*)alloc((size_t)(N_NODES + 1) * 4);
  int* cursor = (int*)alloc((size_t)N_NODES * 4);
  int* hist   = (int*)alloc((size_t)N_NODES * 4);
  int* excl   = (int*)alloc((size_t)N_NODES * 4);
  int* bsum   = (int*)alloc((size_t)64 * 4);
  int* boff   = (int*)alloc((size_t)64 * 4);
  int* spack  = (int*)alloc((size_t)N_EDGES * 4);
  __bf16* Ghi = (__bf16*)alloc((size_t)3 * 131072 * 2);   // 786 KB
  __bf16* Glo = (__bf16*)alloc((size_t)3 * 131072 * 2);
  float* wq   = (float*)alloc((size_t)3 * R_REL * 128 * 4);
  float* wk   = (float*)alloc((size_t)3 * R_REL * 128 * 4);
  __bf16* Qhi = (__bf16*)alloc((size_t)3 * 2048 * 2);
  __bf16* Qlo = (__bf16*)alloc((size_t)3 * 2048 * 2);
  __bf16* Lhi = (__bf16*)alloc((size_t)1024 * 8 * 2);     // 16 KB
  __bf16* Llo = (__bf16*)alloc((size_t)1024 * 8 * 2);

  const int* src = ei;            // edge_index[0]
  const int* dst = ei + N_EDGES;  // edge_index[1]

  // prep (xrfrag + wq + lw + hist-zero + cast)  ->  CSR chain  (13 dispatches total)
  k_prep<<<PREP_B_CAST, 256, 0, stream>>>(W1, W2, W3, q1, k1, q2, k2, q3, k3, lw, x,
                                          Ghi, Glo, wq, wk, Lhi, Llo, hist, xb);
  k_hist<<<CSR_BLOCKS, 256, 0, stream>>>(dst, hist);
  k_scan1<<<50, 1024, 0, stream>>>(hist, excl, bsum, wq, wk, Qhi, Qlo);
  k_scan2<<<1, 64, 0, stream>>>(bsum, boff);
  k_scan3<<<(N_NODES + 255) / 256, 256, 0, stream>>>(excl, boff, rowptr, cursor);
  k_scatter<<<CSR_BLOCKS, 256, 0, stream>>>(src, dst, etype, cursor, spack);

  const int xgrid = XR_XGRID + QK_BLOCKS;   // xr blocks + fused qkx blocks
  const int agrid = (N_NODES + 15) / 16;
  const int fgrid = (N_NODES + 63) / 64;
  const size_t WFL = 131072;
  const size_t QFL = 2048;

  // layer 1
  k_xr<<<xgrid, 512, 0, stream>>>(xb, Ghi, Glo, Qhi, Qlo, qx, kx, XR);
  k_agg_feat<<<agrid, 256, 0, stream>>>(XR, qx, kx, rowptr, spack, b1, hA);
  // layer 2
  k_xr<<<xgrid, 512, 0, stream>>>(hA, Ghi + WFL, Glo + WFL, Qhi + QFL, Qlo + QFL, qx, kx, XR);
  k_agg_feat<<<agrid, 256, 0, stream>>>(XR, qx, kx, rowptr, spack, b2, hB);
  // layer 3
  k_xr<<<xgrid, 512, 0, stream>>>(hB, Ghi + 2 * WFL, Glo + 2 * WFL, Qhi + 2 * QFL, Qlo + 2 * QFL, qx, kx, XR);
  k_agg_feat<<<agrid, 256, 0, stream>>>(XR, qx, kx, rowptr, spack, b3, hA);
  // final linear + log_softmax (MFMA)
  k_final<<<fgrid, 256, 0, stream>>>(hA, Lhi, Llo, lb, outp);
}

// Round 20
// 443.475 us; speedup vs baseline: 1.0319x; 1.0026x over previous
//
#include <hip/hip_runtime.h>
#include <math.h>

#define N_NODES 50000
#define N_EDGES 800000
#define R_REL 8
#define H_DIM 128
#define C_OUT 64

// k_xr geometry: block = (ro-chunk of 64) x (node-group of 4 tiles of 128)
#define XR_TILES 4
#define XR_NTILE ((N_NODES + 127) / 128)                    // 391
#define XR_NGRP ((XR_NTILE + XR_TILES - 1) / XR_TILES)      // 98
#define XR_XGRID (16 * XR_NGRP)                             // 1568
#define QK_BLOCKS ((N_NODES + 127) / 128)                   // 391 (512-thr, 128 nodes)

// CSR build: XCD-confined dst-range binning (verified round 11); scalar loops
#define CSR_RANGES 8
#define CSR_RANGE_NODES (N_NODES / CSR_RANGES)   // 6250
#define CSR_BLOCKS 2048

// k_prep block ranges
#define PREP_B_XR 192                     // xr fragments
#define PREP_B_WQ 204                     // + wq/wk
#define PREP_B_LW0 207
#define PREP_B_LW 211                     // + lw fragments
#define PREP_B_HZ (PREP_B_LW + 196)       // + zero hist (50000 ints)
#define PREP_B_CAST (PREP_B_HZ + 3125)    // + x->bf16 cast (800000 items)

typedef __attribute__((ext_vector_type(8))) __bf16 bf16x8;
typedef __attribute__((ext_vector_type(4))) __bf16 bf16x4;
typedef __attribute__((ext_vector_type(2))) __bf16 bf16x2;
typedef __attribute__((ext_vector_type(4))) float f32x4;

// async global->LDS, 16B per lane; dest must be wave-uniform base + lane*16
__device__ __forceinline__ void gload_lds16(const void* g, void* l) {
  __builtin_amdgcn_global_load_lds(
      (__attribute__((address_space(1))) void*)g,
      (__attribute__((address_space(3))) void*)l,
      16, 0, 0);
}

// ---------------- CSR build (dst-sorted edge list, packed (src<<3)|et) ----------------

__global__ void k_hist(const int* __restrict__ dst, int* __restrict__ hist) {
  const int rng = blockIdx.x & (CSR_RANGES - 1);
  const int rlo = rng * CSR_RANGE_NODES;
  const int rhi = rlo + CSR_RANGE_NODES;
  const int stride = (gridDim.x >> 3) * blockDim.x;
  for (int e = (blockIdx.x >> 3) * blockDim.x + threadIdx.x; e < N_EDGES; e += stride) {
    int d = dst[e];
    if (d >= rlo && d < rhi) atomicAdd(&hist[d], 1);
  }
}

// scan1 blocks [0,49): block-level prefix over hist.  block 49: qkfrag packing.
__global__ __launch_bounds__(1024) void k_scan1(const int* __restrict__ hist,
                                                int* __restrict__ excl, int* __restrict__ bsum,
                                                const float* __restrict__ wq,
                                                const float* __restrict__ wk,
                                                __bf16* __restrict__ Qhi,
                                                __bf16* __restrict__ Qlo) {
  int b = blockIdx.x, tid = threadIdx.x;
  if (b >= 49) {
    // qkfrag: 3*4*64 = 768 items
    int t = tid;
    if (t >= 768) return;
    int lane = t & 63;
    int kb = (t >> 6) & 3;
    int l  = t >> 8;
    int c = lane & 15, quad = lane >> 4;
    const float* Mrow = (c < 8) ? (wq + l * 1024 + c * 128) : (wk + l * 1024 + (c - 8) * 128);
    size_t ob = ((size_t)(l * 4 + kb) * 64 + lane) * 8;
#pragma unroll
    for (int j = 0; j < 8; ++j) {
      float v = Mrow[kb * 32 + quad * 8 + j];
      __bf16 h = (__bf16)v;
      Qhi[ob + j] = h;
      Qlo[ob + j] = (__bf16)(v - (float)h);
    }
    return;
  }
  __shared__ int tmp[1024];
  int idx = b * 1024 + tid;
  int v = (idx < N_NODES) ? hist[idx] : 0;
  tmp[tid] = v;
  __syncthreads();
  for (int off = 1; off < 1024; off <<= 1) {
    int t = (tid >= off) ? tmp[tid - off] : 0;
    __syncthreads();
    tmp[tid] += t;
    __syncthreads();
  }
  if (idx < N_NODES) excl[idx] = tmp[tid] - v;
  if (tid == 1023) bsum[b] = tmp[1023];
}

// 64-lane shfl prefix scan over the 49 block sums
__global__ void k_scan2(const int* __restrict__ bsum, int* __restrict__ boff) {
  const int nb = (N_NODES + 1023) / 1024;   // 49
  int tid = threadIdx.x;
  int v = (tid < nb) ? bsum[tid] : 0;
  int s = v;
#pragma unroll
  for (int off = 1; off < 64; off <<= 1) {
    int t = __shfl_up(s, off);
    if (tid >= off) s += t;
  }
  if (tid < nb) boff[tid] = s - v;
}

__global__ void k_scan3(const int* __restrict__ excl, const int* __restrict__ boff,
                        int* __restrict__ rowptr, int* __restrict__ cursor) {
  int idx = blockIdx.x * blockDim.x + threadIdx.x;
  if (idx < N_NODES) {
    int v = excl[idx] + boff[idx >> 10];
    rowptr[idx] = v;
    cursor[idx] = v;
  }
  if (idx == 0) rowptr[N_NODES] = N_EDGES;
}

__global__ void k_scatter(const int* __restrict__ src, const int* __restrict__ dst,
                          const int* __restrict__ et, int* __restrict__ cursor,
                          int* __restrict__ spack) {
  const int rng = blockIdx.x & (CSR_RANGES - 1);
  const int rlo = rng * CSR_RANGE_NODES;
  const int rhi = rlo + CSR_RANGE_NODES;
  const int stride = (gridDim.x >> 3) * blockDim.x;
  for (int e = (blockIdx.x >> 3) * blockDim.x + threadIdx.x; e < N_EDGES; e += stride) {
    int d = dst[e];
    if (d >= rlo && d < rhi) {
      int p = atomicAdd(&cursor[d], 1);
      spack[p] = (src[e] << 3) | et[e];
    }
  }
}

// ---------------- merged prep: xrfrag + wq + lwfrag + zero-hist + x->bf16 cast ----------

__global__ void k_prep(const float* __restrict__ W1, const float* __restrict__ W2,
                       const float* __restrict__ W3,
                       const float* __restrict__ q1, const float* __restrict__ k1,
                       const float* __restrict__ q2, const float* __restrict__ k2,
                       const float* __restrict__ q3, const float* __restrict__ k3,
                       const float* __restrict__ lw, const float* __restrict__ x,
                       __bf16* __restrict__ Ghi, __bf16* __restrict__ Glo,
                       float* __restrict__ wq, float* __restrict__ wk,
                       __bf16* __restrict__ Lhi, __bf16* __restrict__ Llo,
                       int* __restrict__ hist, __bf16* __restrict__ xb) {
  const int b = blockIdx.x;
  if (b < PREP_B_XR) {
    // xr fragments: 3*64*4*64 = 49152 items
    int t = b * 256 + threadIdx.x;
    int lane = t & 63;
    int kb = (t >> 6) & 3;
    int mt = (t >> 8) & 63;
    int l  = t >> 14;
    int c = lane & 15, quad = lane >> 4;
    const float* W = (l == 0) ? W1 : (l == 1) ? W2 : W3;
    int ro = mt * 16 + c;
    int r = ro >> 7;
    int o = ro & 127;
    int fb = kb * 32 + quad * 8;
    const float* wp = W + ((size_t)r << 14) + (size_t)fb * 128 + o;
    size_t ob = ((size_t)l * 131072) + (((size_t)mt * 4 + kb) * 64 + lane) * 8;
#pragma unroll
    for (int j = 0; j < 8; ++j) {
      float v = wp[j * 128];
      __bf16 h = (__bf16)v;
      Ghi[ob + j] = h;
      Glo[ob + j] = (__bf16)(v - (float)h);
    }
  } else if (b < PREP_B_WQ) {
    // wq/wk: [l][r][f], 3*8*128 = 3072 items
    int idx = (b - PREP_B_XR) * 256 + threadIdx.x;
    if (idx >= 3 * R_REL * 128) return;
    int r = (idx >> 7) & 7;
    int f = idx & 127;
    int l = idx >> 10;
    const float* W  = (l == 0) ? W1 : (l == 1) ? W2 : W3;
    const float* qv = (l == 0) ? q1 : (l == 1) ? q2 : q3;
    const float* kv = (l == 0) ? k1 : (l == 1) ? k2 : k3;
    const float4* row = (const float4*)(W + ((size_t)r << 14) + ((size_t)f << 7));
    const float4* q4 = (const float4*)qv;
    const float4* k4 = (const float4*)kv;
    float sq = 0.f, sk = 0.f;
#pragma unroll 8
    for (int i = 0; i < 32; ++i) {
      float4 w = row[i], qq = q4[i], kk = k4[i];
      sq += w.x * qq.x + w.y * qq.y + w.z * qq.z + w.w * qq.w;
      sk += w.x * kk.x + w.y * kk.y + w.z * kk.z + w.w * kk.w;
    }
    wq[idx] = sq;
    wk[idx] = sk;
  } else if (b < PREP_B_LW0) {
    return;   // reserved
  } else if (b < PREP_B_LW) {
    // lw fragments: [mt][kb][lane] = 4*4*64 = 1024 items
    int t = (b - PREP_B_LW0) * 256 + threadIdx.x;
    if (t >= 1024) return;
    int lane = t & 63;
    int kb = (t >> 6) & 3;
    int mt = t >> 8;
    int c = lane & 15, quad = lane >> 4;
    int cout = mt * 16 + c;
    size_t ob = (size_t)t * 8;
#pragma unroll
    for (int j = 0; j < 8; ++j) {
      int k = kb * 32 + quad * 8 + j;
      float v = lw[(size_t)k * 64 + cout];
      __bf16 h = (__bf16)v;
      Lhi[ob + j] = h;
      Llo[ob + j] = (__bf16)(v - (float)h);
    }
  } else if (b < PREP_B_HZ) {
    // zero hist (replaces hipMemsetAsync dispatch)
    int idx = (b - PREP_B_LW) * 256 + threadIdx.x;
    if (idx < N_NODES) hist[idx] = 0;
  } else {
    // x -> bf16 cast: 800000 bf16x8 items
    int t = (b - PREP_B_HZ) * 256 + threadIdx.x;
    if (t >= N_NODES * H_DIM / 8) return;
    const float4* xv = (const float4*)(x + (size_t)t * 8);
    float4 a = xv[0], bb = xv[1];
    bf16x8 o;
    o[0] = (__bf16)a.x;  o[1] = (__bf16)a.y;  o[2] = (__bf16)a.z;  o[3] = (__bf16)a.w;
    o[4] = (__bf16)bb.x; o[5] = (__bf16)bb.y; o[6] = (__bf16)bb.z; o[7] = (__bf16)bb.w;
    ((bf16x8*)xb)[t] = o;
  }
}

// ---------------- XR GEMM + block-level fused qx/kx (verified round 17: -15 us) ---------

__global__ __launch_bounds__(512, 4) void k_xr(
    const __bf16* __restrict__ xin,
    const __bf16* __restrict__ Ghi, const __bf16* __restrict__ Glo,
    const __bf16* __restrict__ Qhi, const __bf16* __restrict__ Qlo,
    float* __restrict__ qx, float* __restrict__ kx,
    __bf16* __restrict__ XR)
{
  if (blockIdx.x >= XR_XGRID) {
    // ---- qkx path: 128 nodes per 512-thread block ----
    const int bq   = blockIdx.x - XR_XGRID;
    const int tid  = threadIdx.x;
    const int wave = tid >> 6;
    const int lane = tid & 63;
    const int quad = lane >> 4;
    const int c    = lane & 15;
    const int node = bq * 128 + wave * 16 + c;
    const int ncl  = (node < N_NODES) ? node : (N_NODES - 1);

    f32x4 acc = (f32x4){0.f, 0.f, 0.f, 0.f};
#pragma unroll
    for (int kb = 0; kb < 4; ++kb) {
      bf16x8 B = *(const bf16x8*)(xin + (size_t)ncl * 128 + kb * 32 + quad * 8);
      bf16x8 ah = ((const bf16x8*)Qhi)[kb * 64 + lane];
      bf16x8 al = ((const bf16x8*)Qlo)[kb * 64 + lane];
      acc = __builtin_amdgcn_mfma_f32_16x16x32_bf16(ah, B, acc, 0, 0, 0);
      acc = __builtin_amdgcn_mfma_f32_16x16x32_bf16(al, B, acc, 0, 0, 0);
    }
    if (node < N_NODES) {
      float* base = (quad & 2) ? kx : qx;
      int off = (quad & 1) * 4;
      *(float4*)(base + (size_t)node * 8 + off) = make_float4(acc[0], acc[1], acc[2], acc[3]);
    }
    return;
  }

  // ---- XR path ----
  __shared__ bf16x8 sW[2048];            // [0,1024) hi, [1024,2048) lo — 32 KB
  __shared__ __bf16 sT[8192];            // 8 waves x (16 nodes x 64 ro) — 16 KB
  const int tid  = threadIdx.x;
  const int wave = tid >> 6;
  const int lane = tid & 63;
  const int quad = lane >> 4;
  const int c    = lane & 15;
  const int ch   = blockIdx.x & 15;      // ro-chunk: 64 outputs
  const int grp  = blockIdx.x >> 4;      // node group of XR_TILES tiles

  char* sTw = (char*)(sT + wave * 1024); // this wave's 2 KB transpose buffer

  // stage this chunk's weights: 16 KB hi + 16 KB lo
  {
    const float4* gh = (const float4*)(Ghi + (size_t)ch * 8192);
    const float4* gl = (const float4*)(Glo + (size_t)ch * 8192);
    float4* s4 = (float4*)sW;
    gload_lds16(gh + tid, s4 + tid);
    gload_lds16(gh + tid + 512, s4 + tid + 512);
    gload_lds16(gl + tid, s4 + 1024 + tid);
    gload_lds16(gl + tid + 512, s4 + 1024 + tid + 512);
  }

  bool staged = false;
#pragma unroll 1
  for (int t = 0; t < XR_TILES; ++t) {
    const int nb = grp * XR_TILES + t;
    if (nb * 128 >= N_NODES) break;
    const int node = nb * 128 + wave * 16 + c;
    const int nclamp = (node < N_NODES) ? node : (N_NODES - 1);

    bf16x8 B[4];
#pragma unroll
    for (int kb = 0; kb < 4; ++kb)
      B[kb] = *(const bf16x8*)(xin + (size_t)nclamp * 128 + kb * 32 + quad * 8);

    if (!staged) {           // first tile: wait for weight stage (vmcnt drain + barrier)
      __syncthreads();
      staged = true;
    }

    f32x4 acc[4];
#pragma unroll
    for (int ot = 0; ot < 4; ++ot) acc[ot] = (f32x4){0.f, 0.f, 0.f, 0.f};
#pragma unroll
    for (int kb = 0; kb < 4; ++kb) {
#pragma unroll
      for (int ot = 0; ot < 4; ++ot) {
        bf16x8 whi = sW[(ot * 4 + kb) * 64 + lane];
        bf16x8 wlo = sW[1024 + (ot * 4 + kb) * 64 + lane];
        acc[ot] = __builtin_amdgcn_mfma_f32_16x16x32_bf16(whi, B[kb], acc[ot], 0, 0, 0);
        acc[ot] = __builtin_amdgcn_mfma_f32_16x16x32_bf16(wlo, B[kb], acc[ot], 0, 0, 0);
      }
    }

    // intra-wave transpose: acc (node c, ro = ot*16+quad*4+j) -> node-major rows.
#pragma unroll
    for (int ot = 0; ot < 4; ++ot) {
      bf16x4 o;
      o[0] = (__bf16)acc[ot][0];
      o[1] = (__bf16)acc[ot][1];
      o[2] = (__bf16)acc[ot][2];
      o[3] = (__bf16)acc[ot][3];
      int boff = (c << 7) + (((ot << 5) + (quad << 3)) ^ ((c & 7) << 4));
      *(bf16x4*)(sTw + boff) = o;
    }
    // same-wave DS ordering: compiler inserts lgkmcnt wait before dependent reads.
#pragma unroll
    for (int i = 0; i < 2; ++i) {
      int nl  = i * 8 + (lane >> 3);     // node_local 0..15
      int seg = lane & 7;                // 16B segment within the 128B row
      int boff = (nl << 7) + (((seg << 4)) ^ ((nl & 7) << 4));
      bf16x8 v = *(bf16x8*)(sTw + boff);
      int gn = nb * 128 + wave * 16 + nl;
      if (gn < N_NODES)
        *(bf16x8*)(XR + (size_t)gn * 1024 + ch * 64 + seg * 8) = v;
    }
  }
}

// ---------------- phase A: per-dst online-softmax over XR rows -> h (bias+relu fused) ----
// 16-lane groups, 4 nodes per wave.  NEW: all 16 gathers of a chunk issued before
// any accumulation (was 2 serialized batches of 8) — doubles in-flight loads.
// Invalid lanes carry ew=0, so weight-0 contributions are exact.

__global__ __launch_bounds__(256) void k_agg_feat(
    const __bf16* __restrict__ XR, const float* __restrict__ qx, const float* __restrict__ kx,
    const int* __restrict__ rowptr, const int* __restrict__ spack,
    const float* __restrict__ bias, __bf16* __restrict__ hout)
{
  const int lane  = threadIdx.x & 63;
  const int g     = lane >> 4;         // group 0..3 within wave
  const int l16   = lane & 15;         // lane within group
  const int gbase = lane & 48;         // g*16
  const int nd = blockIdx.x * 16 + (threadIdx.x >> 6) * 4 + g;
  const bool alive = nd < N_NODES;

  const int s   = alive ? rowptr[nd] : 0;
  const int deg = alive ? rowptr[nd + 1] - s : 0;

  float m = -INFINITY, sum = 0.f;
  float acc[8];
#pragma unroll
  for (int d = 0; d < 8; ++d) acc[d] = 0.f;

  for (int c0 = 0; c0 < deg; c0 += 16) {
    int idx = c0 + l16;
    bool valid = idx < deg;
    int pk = valid ? spack[s + idx] : 0;
    float a = -INFINITY;
    if (valid) {
      float av = qx[(nd << 3) | (pk & 7)] + kx[pk];
      a = (av >= 0.f) ? av : 0.2f * av;   // leaky relu, slope 0.2
    }
    float cm = a;
#pragma unroll
    for (int off = 8; off > 0; off >>= 1) cm = fmaxf(cm, __shfl_xor(cm, off));
    if (c0 == 0) {
      m = cm;                 // first chunk: no rescale needed
    } else {
      float mnew = fmaxf(m, cm);
      float scale = __expf(m - mnew);
      sum *= scale;
#pragma unroll
      for (int d = 0; d < 8; ++d) acc[d] *= scale;
      m = mnew;
    }
    float ew = valid ? __expf(a - m) : 0.f;
    float cs = ew;
#pragma unroll
    for (int off = 8; off > 0; off >>= 1) cs += __shfl_xor(cs, off);
    sum += cs;

    int cnt = (deg - c0 < 16) ? (deg - c0) : 16;
    // issue ALL gathers for this chunk up front (invalid u have w=0)
    int p[16];
    float w[16];
    bf16x8 v[16];
    if (cnt > 8) {
#pragma unroll
      for (int u = 0; u < 16; ++u) p[u] = __shfl(pk, gbase + u);
#pragma unroll
      for (int u = 0; u < 16; ++u) w[u] = __shfl(ew, gbase + u);
#pragma unroll
      for (int u = 0; u < 16; ++u)
        v[u] = ((const bf16x8*)(XR + ((size_t)p[u] << 7)))[l16];
#pragma unroll
      for (int u = 0; u < 16; ++u) {
#pragma unroll
        for (int d = 0; d < 8; ++d) acc[d] += w[u] * (float)v[u][d];
      }
    } else {
#pragma unroll
      for (int u = 0; u < 8; ++u) p[u] = __shfl(pk, gbase + u);
#pragma unroll
      for (int u = 0; u < 8; ++u) w[u] = __shfl(ew, gbase + u);
#pragma unroll
      for (int u = 0; u < 8; ++u)
        v[u] = ((const bf16x8*)(XR + ((size_t)p[u] << 7)))[l16];
#pragma unroll
      for (int u = 0; u < 8; ++u) {
#pragma unroll
        for (int d = 0; d < 8; ++d) acc[d] += w[u] * (float)v[u][d];
      }
    }
  }

  if (alive) {
    float inv = (deg > 0) ? 1.f / sum : 0.f;
    const float* bb = bias + l16 * 8;
    bf16x8 o;
#pragma unroll
    for (int d = 0; d < 8; ++d) o[d] = (__bf16)fmaxf(acc[d] * inv + bb[d], 0.f);
    ((bf16x8*)hout)[(size_t)nd * 16 + l16] = o;
  }
}

// ---------------- final linear + log_softmax via MFMA ----------------

__global__ __launch_bounds__(256) void k_final(
    const __bf16* __restrict__ h,
    const __bf16* __restrict__ Lhi, const __bf16* __restrict__ Llo,
    const float* __restrict__ lb, float* __restrict__ out)
{
  const int tid  = threadIdx.x;
  const int wave = tid >> 6;
  const int lane = tid & 63;
  const int quad = lane >> 4;
  const int c    = lane & 15;
  const int node = blockIdx.x * 64 + wave * 16 + c;
  const int ncl  = (node < N_NODES) ? node : (N_NODES - 1);

  bf16x8 B[4];
#pragma unroll
  for (int kb = 0; kb < 4; ++kb)
    B[kb] = *(const bf16x8*)(h + (size_t)ncl * 128 + kb * 32 + quad * 8);

  f32x4 acc[4];
#pragma unroll
  for (int mt = 0; mt < 4; ++mt) acc[mt] = (f32x4){0.f, 0.f, 0.f, 0.f};

#pragma unroll
  for (int mt = 0; mt < 4; ++mt) {
#pragma unroll
    for (int kb = 0; kb < 4; ++kb) {
      bf16x8 ah = ((const bf16x8*)Lhi)[(mt * 4 + kb) * 64 + lane];
      bf16x8 al = ((const bf16x8*)Llo)[(mt * 4 + kb) * 64 + lane];
      acc[mt] = __builtin_amdgcn_mfma_f32_16x16x32_bf16(ah, B[kb], acc[mt], 0, 0, 0);
      acc[mt] = __builtin_amdgcn_mfma_f32_16x16x32_bf16(al, B[kb], acc[mt], 0, 0, 0);
    }
  }

  float v[16];
#pragma unroll
  for (int mt = 0; mt < 4; ++mt) {
    float4 bb = *(const float4*)(lb + mt * 16 + quad * 4);
    v[mt * 4 + 0] = acc[mt][0] + bb.x;
    v[mt * 4 + 1] = acc[mt][1] + bb.y;
    v[mt * 4 + 2] = acc[mt][2] + bb.z;
    v[mt * 4 + 3] = acc[mt][3] + bb.w;
  }
  float mx = v[0];
#pragma unroll
  for (int i = 1; i < 16; ++i) mx = fmaxf(mx, v[i]);
  mx = fmaxf(mx, __shfl_xor(mx, 16));
  mx = fmaxf(mx, __shfl_xor(mx, 32));
  float ssum = 0.f;
#pragma unroll
  for (int i = 0; i < 16; ++i) ssum += __expf(v[i] - mx);
  ssum += __shfl_xor(ssum, 16);
  ssum += __shfl_xor(ssum, 32);
  float lse = mx + __logf(ssum);

  if (node < N_NODES) {
    float* op = out + (size_t)node * 64 + quad * 4;
#pragma unroll
    for (int mt = 0; mt < 4; ++mt) {
      *(float4*)(op + mt * 16) = make_float4(v[mt * 4 + 0] - lse, v[mt * 4 + 1] - lse,
                                             v[mt * 4 + 2] - lse, v[mt * 4 + 3] - lse);
    }
  }
}

// ---------------- launch ----------------

extern "C" void kernel_launch(void* const* d_in, const int* in_sizes, int n_in,
                              void* d_out, int out_size, void* d_ws, size_t ws_size,
                              hipStream_t stream) {
  const float* x   = (const float*)d_in[0];
  const int* ei    = (const int*)d_in[1];
  const int* etype = (const int*)d_in[2];
  const float* W1 = (const float*)d_in[3];
  const float* q1 = (const float*)d_in[4];
  const float* k1 = (const float*)d_in[5];
  const float* b1 = (const float*)d_in[6];
  const float* W2 = (const float*)d_in[7];
  const float* q2 = (const float*)d_in[8];
  const float* k2 = (const float*)d_in[9];
  const float* b2 = (const float*)d_in[10];
  const float* W3 = (const float*)d_in[11];
  const float* q3 = (const float*)d_in[12];
  const float* k3 = (const float*)d_in[13];
  const float* b3 = (const float*)d_in[14];
  const float* lw = (const float*)d_in[15];
  const float* lb = (const float*)d_in[16];
  float* outp = (float*)d_out;

  char* p = (char*)d_ws;
  auto alloc = [&](size_t bytes) {
    char* r = p;
    p += (bytes + 255) & ~(size_t)255;
    return r;
  };
  __bf16* XR  = (__bf16*)alloc((size_t)N_NODES * R_REL * H_DIM * 2);  // 102.4 MB
  __bf16* xb  = (__bf16*)alloc((size_t)N_NODES * H_DIM * 2);          // 12.8 MB
  __bf16* hA  = (__bf16*)alloc((size_t)N_NODES * H_DIM * 2);
  __bf16* hB  = (__bf16*)alloc((size_t)N_NODES * H_DIM * 2);
  float* qx   = (float*)alloc((size_t)N_NODES * R_REL * 4);
  float* kx   = (float*)alloc((size_t)N_NODES * R_REL * 4);
  int* rowptr = (int*)alloc((size_t)(N_NODES + 1) * 4);
  int* cursor = (int*)alloc((size_t)N_NODES * 4);
  int* hist   = (int*)alloc((size_t)N_NODES * 4);
  int* excl   = (int*)alloc((size_t)N_NODES * 4);
  int* bsum   = (int*)alloc((size_t)64 * 4);
  int* boff   = (int*)alloc((size_t)64 * 4);
  int* spack  = (int*)alloc((size_t)N_EDGES * 4);
  __bf16* Ghi = (__bf16*)alloc((size_t)3 * 131072 * 2);   // 786 KB
  __bf16* Glo = (__bf16*)alloc((size_t)3 * 131072 * 2);
  float* wq   = (float*)alloc((size_t)3 * R_REL * 128 * 4);
  float* wk   = (float*)alloc((size_t)3 * R_REL * 128 * 4);
  __bf16* Qhi = (__bf16*)alloc((size_t)3 * 2048 * 2);
  __bf16* Qlo = (__bf16*)alloc((size_t)3 * 2048 * 2);
  __bf16* Lhi = (__bf16*)alloc((size_t)1024 * 8 * 2);     // 16 KB
  __bf16* Llo = (__bf16*)alloc((size_t)1024 * 8 * 2);

  const int* src = ei;            // edge_index[0]
  const int* dst = ei + N_EDGES;  // edge_index[1]

  // prep (xrfrag + wq + lw + hist-zero + cast)  ->  CSR chain  (13 dispatches total)
  k_prep<<<PREP_B_CAST, 256, 0, stream>>>(W1, W2, W3, q1, k1, q2, k2, q3, k3, lw, x,
                                          Ghi, Glo, wq, wk, Lhi, Llo, hist, xb);
  k_hist<<<CSR_BLOCKS, 256, 0, stream>>>(dst, hist);
  k_scan1<<<50, 1024, 0, stream>>>(hist, excl, bsum, wq, wk, Qhi, Qlo);
  k_scan2<<<1, 64, 0, stream>>>(bsum, boff);
  k_scan3<<<(N_NODES + 255) / 256, 256, 0, stream>>>(excl, boff, rowptr, cursor);
  k_scatter<<<CSR_BLOCKS, 256, 0, stream>>>(src, dst, etype, cursor, spack);

  const int xgrid = XR_XGRID + QK_BLOCKS;   // xr blocks + fused qkx blocks
  const int agrid = (N_NODES + 15) / 16;
  const int fgrid = (N_NODES + 63) / 64;
  const size_t WFL = 131072;
  const size_t QFL = 2048;

  // layer 1
  k_xr<<<xgrid, 512, 0, stream>>>(xb, Ghi, Glo, Qhi, Qlo, qx, kx, XR);
  k_agg_feat<<<agrid, 256, 0, stream>>>(XR, qx, kx, rowptr, spack, b1, hA);
  // layer 2
  k_xr<<<xgrid, 512, 0, stream>>>(hA, Ghi + WFL, Glo + WFL, Qhi + QFL, Qlo + QFL, qx, kx, XR);
  k_agg_feat<<<agrid, 256, 0, stream>>>(XR, qx, kx, rowptr, spack, b2, hB);
  // layer 3
  k_xr<<<xgrid, 512, 0, stream>>>(hB, Ghi + 2 * WFL, Glo + 2 * WFL, Qhi + 2 * QFL, Qlo + 2 * QFL, qx, kx, XR);
  k_agg_feat<<<agrid, 256, 0, stream>>>(XR, qx, kx, rowptr, spack, b3, hA);
  // final linear + log_softmax (MFMA)
  k_final<<<fgrid, 256, 0, stream>>>(hA, Lhi, Llo, lb, outp);
}